// Round 5
// baseline (578.487 us; speedup 1.0000x reference)
//
#include <hip/hip_runtime.h>
#include <hip/hip_bf16.h>

#define NT 100000
#define BQ 1024
#define DD 256
#define NTILE 64
#define NTILES 1563        // ceil(100000/64); grid = one block per tile
#define REPS 16            // global accumulator replicas

typedef __attribute__((ext_vector_type(8))) short bf16x8;
typedef __attribute__((ext_vector_type(4))) float f32x4;

__device__ __forceinline__ unsigned f2bf(float x) {
    union { float f; unsigned u; } a; a.f = x;
    return (a.u + 0x7fffu + ((a.u >> 16) & 1u)) >> 16;  // RNE
}

// ---- init: normalize q -> bf16 (1 wave/row) ----
__global__ void init_k(const float* __restrict__ q, unsigned short* __restrict__ qn) {
    int lane = threadIdx.x & 63, wid = threadIdx.x >> 6;
    int row = blockIdx.x * 4 + wid;
    float4 v = ((const float4*)q)[(size_t)row * 64 + lane];
    float s = v.x * v.x + v.y * v.y + v.z * v.z + v.w * v.w;
    #pragma unroll
    for (int m = 1; m < 64; m <<= 1) s += __shfl_xor(s, m, 64);
    float sc = rsqrtf(fmaxf(s, 1e-24f));
    uint2 pk;
    pk.x = f2bf(v.x * sc) | (f2bf(v.y * sc) << 16);
    pk.y = f2bf(v.z * sc) | (f2bf(v.w * sc) << 16);
    *(uint2*)&qn[(size_t)row * DD + lane * 4] = pk;
}

// ---- main: block = one 64-row t-tile (staged + fused-normalized into LDS),
// loops all 8 m-chunks of q (L2-resident qn). A=t (D row->n), B=q (D col->m).
// STATELESS chunk loop: partials are quad-reduced and flushed to replicated
// global accumulators via atomicAdd immediately (no register/LDS state carried
// across chunks — the R3/R4 spill killer). Last-done block finalizes. ----
__global__ __launch_bounds__(256, 4) void knn_main(
        const float* __restrict__ t_raw,
        const unsigned short* __restrict__ qn,
        float* __restrict__ accs,
        int* __restrict__ cnts,
        float* __restrict__ out) {
    __shared__ unsigned short t_lds[NTILE * DD];   // 32 KB, XOR-swizzled 16B chunks
    __shared__ int s_last;

    const int tid = threadIdx.x;
    const int lane = tid & 63, w = tid >> 6;
    const int quad = lane >> 4, l16 = lane & 15;
    const int swz = l16 & 7;
    const int n0 = blockIdx.x * NTILE;

    // ---- stage + fused-normalize: wave w -> rows w*16..w*16+15 ----
    #pragma unroll
    for (int b = 0; b < 2; ++b) {
        float4 v[8];
        #pragma unroll
        for (int j = 0; j < 8; ++j) {
            int n = n0 + w * 16 + b * 8 + j;
            v[j] = (n < NT) ? ((const float4*)t_raw)[(size_t)n * 64 + lane]
                            : make_float4(0.f, 0.f, 0.f, 0.f);
        }
        #pragma unroll
        for (int j = 0; j < 8; ++j) {
            int r = w * 16 + b * 8 + j;
            float s = v[j].x * v[j].x + v[j].y * v[j].y + v[j].z * v[j].z + v[j].w * v[j].w;
            #pragma unroll
            for (int m = 1; m < 64; m <<= 1) s += __shfl_xor(s, m, 64);
            float sc = rsqrtf(fmaxf(s, 1e-24f));
            uint2 pk;
            pk.x = f2bf(v[j].x * sc) | (f2bf(v[j].y * sc) << 16);
            pk.y = f2bf(v[j].z * sc) | (f2bf(v[j].w * sc) << 16);
            int kb16 = lane >> 1, half = lane & 1;
            *(uint2*)&t_lds[r * DD + (((kb16 ^ (r & 7)) << 3) + (half << 2))] = pk;
        }
    }
    __syncthreads();

    const bool full = (n0 + NTILE <= NT);
    float* acc_e  = accs + (size_t)(blockIdx.x & (REPS - 1)) * 2048;
    float* acc_ed = acc_e + 1024;

    #pragma unroll 1   // stateless body: keep code small, live set ~120 VGPR
    for (int c = 0; c < 8; ++c) {
        bf16x8 qf[2][8];
        const unsigned short* qbase =
            qn + (size_t)(c * 128 + w * 32 + l16) * DD + quad * 8;
        #pragma unroll
        for (int mi = 0; mi < 2; ++mi)
            #pragma unroll
            for (int ks = 0; ks < 8; ++ks)
                qf[mi][ks] = *(const bf16x8*)(qbase + mi * 16 * DD + ks * 32);

        f32x4 acc[4][2];
        #pragma unroll
        for (int ni = 0; ni < 4; ++ni)
            #pragma unroll
            for (int mi = 0; mi < 2; ++mi)
                acc[ni][mi] = (f32x4){0.f, 0.f, 0.f, 0.f};

        #pragma unroll
        for (int ks = 0; ks < 8; ++ks) {
            bf16x8 a[4];
            #pragma unroll
            for (int ni = 0; ni < 4; ++ni)
                a[ni] = *(const bf16x8*)
                    &t_lds[(ni * 16 + l16) * DD + (((ks * 4 + quad) ^ swz) << 3)];
            #pragma unroll
            for (int ni = 0; ni < 4; ++ni)
                #pragma unroll
                for (int mi = 0; mi < 2; ++mi)
                    acc[ni][mi] = __builtin_amdgcn_mfma_f32_16x16x32_bf16(
                        a[ni], qf[mi][ks], acc[ni][mi], 0, 0, 0);
        }

        float te0 = 0.f, te1 = 0.f, td0 = 0.f, td1 = 0.f;
        if (full) {
            #pragma unroll
            for (int ni = 0; ni < 4; ++ni)
                #pragma unroll
                for (int r = 0; r < 4; ++r) {
                    float d0 = __builtin_amdgcn_sqrtf(fmaxf(fmaf(-2.f, acc[ni][0][r], 2.f), 0.f));
                    float e0 = __expf(-10.f * d0);
                    te0 += e0; td0 = fmaf(e0, d0, td0);
                    float d1 = __builtin_amdgcn_sqrtf(fmaxf(fmaf(-2.f, acc[ni][1][r], 2.f), 0.f));
                    float e1 = __expf(-10.f * d1);
                    te1 += e1; td1 = fmaf(e1, d1, td1);
                }
        } else {
            #pragma unroll
            for (int ni = 0; ni < 4; ++ni)
                #pragma unroll
                for (int r = 0; r < 4; ++r) {
                    bool valid = (n0 + ni * 16 + quad * 4 + r) < NT;
                    float d0 = __builtin_amdgcn_sqrtf(fmaxf(fmaf(-2.f, acc[ni][0][r], 2.f), 0.f));
                    float e0 = valid ? __expf(-10.f * d0) : 0.f;
                    te0 += e0; td0 = fmaf(e0, d0, td0);
                    float d1 = __builtin_amdgcn_sqrtf(fmaxf(fmaf(-2.f, acc[ni][1][r], 2.f), 0.f));
                    float e1 = valid ? __expf(-10.f * d1) : 0.f;
                    te1 += e1; td1 = fmaf(e1, d1, td1);
                }
        }
        // sum across quads (the n direction within the wave): 2 shuffle levels
        te0 += __shfl_xor(te0, 16, 64); te0 += __shfl_xor(te0, 32, 64);
        te1 += __shfl_xor(te1, 16, 64); te1 += __shfl_xor(te1, 32, 64);
        td0 += __shfl_xor(td0, 16, 64); td0 += __shfl_xor(td0, 32, 64);
        td1 += __shfl_xor(td1, 16, 64); td1 += __shfl_xor(td1, 32, 64);
        if (quad == 0) {
            int m0 = c * 128 + w * 32 + l16;
            atomicAdd(&acc_e[m0],       te0);
            atomicAdd(&acc_e[m0 + 16],  te1);
            atomicAdd(&acc_ed[m0],      td0);
            atomicAdd(&acc_ed[m0 + 16], td1);
        }
    }

    // ---- done-counter finalize (no spin) ----
    __threadfence();
    __syncthreads();
    if (tid == 0) s_last = (atomicAdd(&cnts[0], 1) == NTILES - 1) ? 1 : 0;
    __syncthreads();
    if (s_last) {
        for (int i = tid; i < BQ; i += 256) {
            float e = 0.f, d = 0.f;
            #pragma unroll
            for (int rp = 0; rp < REPS; ++rp) {
                e += __hip_atomic_load(&accs[rp * 2048 + i],
                                       __ATOMIC_RELAXED, __HIP_MEMORY_SCOPE_AGENT);
                d += __hip_atomic_load(&accs[rp * 2048 + 1024 + i],
                                       __ATOMIC_RELAXED, __HIP_MEMORY_SCOPE_AGENT);
            }
            out[i] = d / e;
        }
    }
}

extern "C" void kernel_launch(void* const* d_in, const int* in_sizes, int n_in,
                              void* d_out, int out_size, void* d_ws, size_t ws_size,
                              hipStream_t stream) {
    const float* q = (const float*)d_in[0];   // [1024,256] fp32
    const float* t = (const float*)d_in[1];   // [100000,256] fp32
    float* out = (float*)d_out;               // [1024] fp32

    char* ws = (char*)d_ws;
    float* accs = (float*)ws;                                   // REPS*2048 f = 128 KB
    int* cnts = (int*)(ws + (size_t)REPS * 2048 * sizeof(float));
    unsigned short* qn =
        (unsigned short*)(ws + (size_t)REPS * 2048 * sizeof(float) + 256);

    hipMemsetAsync(ws, 0, (size_t)REPS * 2048 * sizeof(float) + 256, stream);
    init_k<<<BQ / 4, 256, 0, stream>>>(q, qn);
    knn_main<<<NTILES, 256, 0, stream>>>(t, qn, accs, cnts, out);
}

// Round 6
// 437.849 us; speedup vs baseline: 1.3212x; 1.3212x over previous
//
#include <hip/hip_runtime.h>
#include <hip/hip_bf16.h>

#define NT 100000
#define NT_PAD 100032      // 1563 * 64
#define BQ 1024
#define DD 256
#define NTILE 64
#define NTILES 1563        // ceil(100000/64)
#define NGROUPS 128        // n-groups; grid = NGROUPS * 8 m-chunks
#define REPS 8             // global accumulator replicas

typedef __attribute__((ext_vector_type(8))) short bf16x8;
typedef __attribute__((ext_vector_type(4))) float f32x4;

__device__ __forceinline__ unsigned f2bf(float x) {
    union { float f; unsigned u; } a; a.f = x;
    return (a.u + 0x7fffu + ((a.u >> 16) & 1u)) >> 16;  // RNE
}

__device__ __forceinline__ void gl_lds16(const void* g, void* l) {
    __builtin_amdgcn_global_load_lds(
        (const __attribute__((address_space(1))) unsigned int*)g,
        (__attribute__((address_space(3))) unsigned int*)l, 16, 0, 0);
}

// ---- prep: normalize q rows AND t rows -> bf16 (1 wave/row); zero-pad t tail ----
__global__ void prep(const float* __restrict__ q, const float* __restrict__ t,
                     unsigned short* __restrict__ qn, unsigned short* __restrict__ tn) {
    int lane = threadIdx.x & 63, wid = threadIdx.x >> 6;
    int row = blockIdx.x * 4 + wid;          // grid covers BQ + NT_PAD rows
    const float* src;
    unsigned short* dst;
    bool zero = false;
    if (row < BQ) { src = q + (size_t)row * DD; dst = qn + (size_t)row * DD; }
    else {
        int tr = row - BQ;
        src = t + (size_t)tr * DD;
        dst = tn + (size_t)tr * DD;
        zero = (tr >= NT);
    }
    uint2 pk; pk.x = 0u; pk.y = 0u;
    if (!zero) {
        float4 v = ((const float4*)src)[lane];
        float s = v.x * v.x + v.y * v.y + v.z * v.z + v.w * v.w;
        #pragma unroll
        for (int m = 1; m < 64; m <<= 1) s += __shfl_xor(s, m, 64);
        float sc = rsqrtf(fmaxf(s, 1e-24f));
        pk.x = f2bf(v.x * sc) | (f2bf(v.y * sc) << 16);
        pk.y = f2bf(v.z * sc) | (f2bf(v.w * sc) << 16);
    }
    *(uint2*)&dst[lane * 4] = pk;
}

// ---- main ----
// Grid 1024 = 128 n-groups (blockIdx>>3) x 8 m-chunks (blockIdx&7); adjacent
// blocks share the tile sequence (L3 serves siblings). Block = 4 waves in a
// 2n x 2m grid; wave tile = 32n x 64m (ni=2, mi=4): each LDS A-read feeds 4
// MFMAs -> 64 KB LDS-read per block-tile (R2: 131 KB). qf[4][8] register-
// resident across all tiles. Per-lane partials se[4]/sd[4] (static mi index
// ONLY — runtime indexing = scratch spill, the R3/R4/R5 killer). Double-
// buffered DMA staging, ONE barrier per tile. Last-done block finalizes.
__global__ __launch_bounds__(256, 2) void knn_main(
        const unsigned short* __restrict__ tn,
        const unsigned short* __restrict__ qn,
        float* __restrict__ accs,
        int* __restrict__ cnts,
        float* __restrict__ out) {
    __shared__ unsigned short t_lds[2][NTILE * DD];   // 2 x 32 KB
    __shared__ int s_last;

    const int tid = threadIdx.x;
    const int lane = tid & 63, w = tid >> 6;
    const int quad = lane >> 4, l16 = lane & 15;
    const int g  = blockIdx.x >> 3;
    const int mc = blockIdx.x & 7;
    const int wn = (w >> 1) * 32;            // wave n-offset in tile
    const int mrow0 = mc * 128 + (w & 1) * 64;   // wave m-base (+ mi*16 + l16)

    // stage tile g into buf 0: 8 DMA instrs/wave, 2 rows each, XOR-swizzled src
    {
        const char* base = (const char*)tn + (size_t)g * NTILE * DD * 2;
        #pragma unroll
        for (int j = 0; j < 8; ++j) {
            int row = w * 16 + j * 2 + (lane >> 5);
            gl_lds16(base + row * 512 + (((lane & 31) ^ (row & 7)) << 4),
                     &t_lds[0][(w * 16 + j * 2) * DD]);
        }
    }

    // q fragments resident: [mi][ks], 128 VGPR
    bf16x8 qf[4][8];
    {
        const unsigned short* qb = qn + (size_t)(mrow0 + l16) * DD + quad * 8;
        #pragma unroll
        for (int mi = 0; mi < 4; ++mi)
            #pragma unroll
            for (int ks = 0; ks < 8; ++ks)
                qf[mi][ks] = *(const bf16x8*)(qb + mi * 16 * DD + ks * 32);
    }

    __syncthreads();   // buf0 DMA drained (vmcnt0 at barrier)

    float se[4] = {0.f, 0.f, 0.f, 0.f}, sd[4] = {0.f, 0.f, 0.f, 0.f};
    int cur = 0;

    for (int ti = g; ti < NTILES; ti += NGROUPS) {
        // prefetch next tile into the other buffer (covered by MFMA+epilogue)
        int tnx = ti + NGROUPS;
        if (tnx < NTILES) {
            const char* base = (const char*)tn + (size_t)tnx * NTILE * DD * 2;
            unsigned short* dstbuf = t_lds[cur ^ 1];
            #pragma unroll
            for (int j = 0; j < 8; ++j) {
                int row = w * 16 + j * 2 + (lane >> 5);
                gl_lds16(base + row * 512 + (((lane & 31) ^ (row & 7)) << 4),
                         &dstbuf[(w * 16 + j * 2) * DD]);
            }
        }

        f32x4 acc[2][4];
        #pragma unroll
        for (int ni = 0; ni < 2; ++ni)
            #pragma unroll
            for (int mi = 0; mi < 4; ++mi)
                acc[ni][mi] = (f32x4){0.f, 0.f, 0.f, 0.f};

        const unsigned short* tl = t_lds[cur];
        #pragma unroll
        for (int ks = 0; ks < 8; ++ks) {
            bf16x8 a[2];
            #pragma unroll
            for (int ni = 0; ni < 2; ++ni)
                a[ni] = *(const bf16x8*)
                    &tl[(wn + ni * 16 + l16) * DD + (((ks * 4 + quad) ^ (l16 & 7)) << 3)];
            #pragma unroll
            for (int ni = 0; ni < 2; ++ni)
                #pragma unroll
                for (int mi = 0; mi < 4; ++mi)
                    acc[ni][mi] = __builtin_amdgcn_mfma_f32_16x16x32_bf16(
                        a[ni], qf[mi][ks], acc[ni][mi], 0, 0, 0);
        }

        // epilogue: accumulate into per-lane partials (no shuffles, no LDS)
        const int n0 = ti * NTILE;
        if (n0 + NTILE <= NT) {
            #pragma unroll
            for (int ni = 0; ni < 2; ++ni)
                #pragma unroll
                for (int mi = 0; mi < 4; ++mi)
                    #pragma unroll
                    for (int r = 0; r < 4; ++r) {
                        float d = __builtin_amdgcn_sqrtf(
                            fmaxf(fmaf(-2.f, acc[ni][mi][r], 2.f), 0.f));
                        float e = __expf(-10.f * d);
                        se[mi] += e;
                        sd[mi] = fmaf(e, d, sd[mi]);
                    }
        } else {
            #pragma unroll
            for (int ni = 0; ni < 2; ++ni)
                #pragma unroll
                for (int mi = 0; mi < 4; ++mi)
                    #pragma unroll
                    for (int r = 0; r < 4; ++r) {
                        float d = __builtin_amdgcn_sqrtf(
                            fmaxf(fmaf(-2.f, acc[ni][mi][r], 2.f), 0.f));
                        bool valid = (n0 + wn + ni * 16 + quad * 4 + r) < NT;
                        float e = valid ? __expf(-10.f * d) : 0.f;
                        se[mi] += e;
                        sd[mi] = fmaf(e, d, sd[mi]);
                    }
        }

        __syncthreads();   // all waves done with cur; next DMA drained
        cur ^= 1;
    }

    // ---- end: quad-reduce (2 shuffles) + replicated atomics ----
    float* ae = accs + (size_t)(blockIdx.x & (REPS - 1)) * 2048;
    float* ad = ae + 1024;
    #pragma unroll
    for (int mi = 0; mi < 4; ++mi) {
        float e = se[mi], d = sd[mi];
        e += __shfl_xor(e, 16, 64); e += __shfl_xor(e, 32, 64);
        d += __shfl_xor(d, 16, 64); d += __shfl_xor(d, 32, 64);
        if (quad == 0) {
            atomicAdd(&ae[mrow0 + mi * 16 + l16], e);
            atomicAdd(&ad[mrow0 + mi * 16 + l16], d);
        }
    }

    // ---- done-counter finalize ----
    __threadfence();
    __syncthreads();
    if (tid == 0) s_last = (atomicAdd(&cnts[0], 1) == (int)gridDim.x - 1) ? 1 : 0;
    __syncthreads();
    if (s_last) {
        for (int i = tid; i < BQ; i += 256) {
            float e = 0.f, d = 0.f;
            #pragma unroll
            for (int rp = 0; rp < REPS; ++rp) {
                e += __hip_atomic_load(&accs[rp * 2048 + i],
                                       __ATOMIC_RELAXED, __HIP_MEMORY_SCOPE_AGENT);
                d += __hip_atomic_load(&accs[rp * 2048 + 1024 + i],
                                       __ATOMIC_RELAXED, __HIP_MEMORY_SCOPE_AGENT);
            }
            out[i] = d / e;
        }
    }
}

extern "C" void kernel_launch(void* const* d_in, const int* in_sizes, int n_in,
                              void* d_out, int out_size, void* d_ws, size_t ws_size,
                              hipStream_t stream) {
    const float* q = (const float*)d_in[0];   // [1024,256] fp32
    const float* t = (const float*)d_in[1];   // [100000,256] fp32
    float* out = (float*)d_out;               // [1024] fp32

    char* ws = (char*)d_ws;
    float* accs = (float*)ws;                                   // REPS*2048 f = 64 KB
    int* cnts = (int*)(ws + (size_t)REPS * 2048 * sizeof(float));
    unsigned short* qn =
        (unsigned short*)(ws + (size_t)REPS * 2048 * sizeof(float) + 256);
    unsigned short* tn = qn + (size_t)BQ * DD;                  // 51.2 MB

    hipMemsetAsync(ws, 0, (size_t)REPS * 2048 * sizeof(float) + 256, stream);
    prep<<<(BQ + NT_PAD) / 4, 256, 0, stream>>>(q, t, qn, tn);
    knn_main<<<NGROUPS * 8, 256, 0, stream>>>(tn, qn, accs, cnts, out);
}

// Round 7
// 241.661 us; speedup vs baseline: 2.3938x; 1.8118x over previous
//
#include <hip/hip_runtime.h>
#include <hip/hip_bf16.h>

#define NT 100000
#define NT_PAD 100032      // 1563 * 64
#define BQ 1024
#define DD 256
#define NTILE 64
#define NTILES 1563        // ceil(100000/64)
#define NGROUPS 64         // n-groups
#define GRID 512           // 64 n-groups x 8 m-chunks; exactly 2 blocks/CU
#define REPS 8             // global accumulator replicas

typedef __attribute__((ext_vector_type(8))) short bf16x8;
typedef __attribute__((ext_vector_type(4))) float f32x4;

__device__ __forceinline__ unsigned f2bf(float x) {
    union { float f; unsigned u; } a; a.f = x;
    return (a.u + 0x7fffu + ((a.u >> 16) & 1u)) >> 16;  // RNE
}

__device__ __forceinline__ void gl_lds16(const void* g, void* l) {
    __builtin_amdgcn_global_load_lds(
        (const __attribute__((address_space(1))) unsigned int*)g,
        (__attribute__((address_space(3))) unsigned int*)l, 16, 0, 0);
}

// ---- prep: normalize q rows AND t rows -> bf16 (1 wave/row); zero-pad t tail ----
__global__ void prep(const float* __restrict__ q, const float* __restrict__ t,
                     unsigned short* __restrict__ qn, unsigned short* __restrict__ tn) {
    int lane = threadIdx.x & 63, wid = threadIdx.x >> 6;
    int row = blockIdx.x * 4 + wid;          // grid covers BQ + NT_PAD rows
    const float* src;
    unsigned short* dst;
    bool zero = false;
    if (row < BQ) { src = q + (size_t)row * DD; dst = qn + (size_t)row * DD; }
    else {
        int tr = row - BQ;
        src = t + (size_t)tr * DD;
        dst = tn + (size_t)tr * DD;
        zero = (tr >= NT);
    }
    uint2 pk; pk.x = 0u; pk.y = 0u;
    if (!zero) {
        float4 v = ((const float4*)src)[lane];
        float s = v.x * v.x + v.y * v.y + v.z * v.z + v.w * v.w;
        #pragma unroll
        for (int m = 1; m < 64; m <<= 1) s += __shfl_xor(s, m, 64);
        float sc = rsqrtf(fmaxf(s, 1e-24f));
        pk.x = f2bf(v.x * sc) | (f2bf(v.y * sc) << 16);
        pk.y = f2bf(v.z * sc) | (f2bf(v.w * sc) << 16);
    }
    *(uint2*)&dst[lane * 4] = pk;
}

// ---- main ----
// Grid 512: g = blockIdx & 63 (n-group), mc = blockIdx >> 6 (m-chunk).
// CRITICAL: the 8 m-siblings of a tile are 64 apart in blockIdx -> same
// blockIdx%8 -> same XCD -> the t-tile is fetched into that XCD's L2 ONCE
// (R2/R6 had siblings on 8 different XCDs: 200-260 MB refetch, the real
// bottleneck). Per XCD: 64 blocks = its 64 residency slots at 2 blocks/CU.
// Block = 4 waves, each 64n x 32m: qf[2][8] register-resident (64 VGPR —
// the ONLY residency proven not to spill; mi=4 spilled in R4/R5/R6).
// acc[4][2] = 32 regs. DMA-staged bf16 t-tiles, double-buffered, ONE
// barrier per tile. Persistent per-lane se[2]/sd[2] (static indices only).
__global__ __launch_bounds__(256, 2) void knn_main(
        const unsigned short* __restrict__ tn,
        const unsigned short* __restrict__ qn,
        float* __restrict__ accs,
        int* __restrict__ cnts,
        float* __restrict__ out) {
    __shared__ unsigned short t_lds[2][NTILE * DD];   // 2 x 32 KB
    __shared__ int s_last;

    const int tid = threadIdx.x;
    const int lane = tid & 63, w = tid >> 6;
    const int quad = lane >> 4, l16 = lane & 15;
    const int swz = l16 & 7;
    const int g  = blockIdx.x & 63;
    const int mc = blockIdx.x >> 6;
    const int mrow0 = mc * 128 + w * 32;     // wave m-base (+ mi*16 + l16)

    // stage tile g into buf 0 (XOR-swizzled 16B chunks: LDS[r][c]=G[r][c^(r&7)])
    {
        const char* base = (const char*)tn + (size_t)g * NTILE * DD * 2;
        #pragma unroll
        for (int j = 0; j < 8; ++j) {
            int row = w * 16 + j * 2 + (lane >> 5);
            gl_lds16(base + row * 512 + (((lane & 31) ^ (row & 7)) << 4),
                     &t_lds[0][(w * 16 + j * 2) * DD]);
        }
    }

    // q fragments resident: [mi][ks] = 64 VGPR
    bf16x8 qf[2][8];
    {
        const unsigned short* qb = qn + (size_t)(mrow0 + l16) * DD + quad * 8;
        #pragma unroll
        for (int mi = 0; mi < 2; ++mi)
            #pragma unroll
            for (int ks = 0; ks < 8; ++ks)
                qf[mi][ks] = *(const bf16x8*)(qb + mi * 16 * DD + ks * 32);
    }

    __syncthreads();   // buf0 DMA drained

    float se[2] = {0.f, 0.f}, sd[2] = {0.f, 0.f};
    int cur = 0;

    for (int ti = g; ti < NTILES; ti += NGROUPS) {
        // prefetch next tile into other buffer (drained at this iter's barrier)
        int tnx = ti + NGROUPS;
        if (tnx < NTILES) {
            const char* base = (const char*)tn + (size_t)tnx * NTILE * DD * 2;
            unsigned short* dstbuf = t_lds[cur ^ 1];
            #pragma unroll
            for (int j = 0; j < 8; ++j) {
                int row = w * 16 + j * 2 + (lane >> 5);
                gl_lds16(base + row * 512 + (((lane & 31) ^ (row & 7)) << 4),
                         &dstbuf[(w * 16 + j * 2) * DD]);
            }
        }

        f32x4 acc[4][2];
        #pragma unroll
        for (int ni = 0; ni < 4; ++ni)
            #pragma unroll
            for (int mi = 0; mi < 2; ++mi)
                acc[ni][mi] = (f32x4){0.f, 0.f, 0.f, 0.f};

        const unsigned short* tl = t_lds[cur];
        #pragma unroll
        for (int ks = 0; ks < 8; ++ks) {
            bf16x8 a[4];
            #pragma unroll
            for (int ni = 0; ni < 4; ++ni)
                a[ni] = *(const bf16x8*)
                    &tl[(ni * 16 + l16) * DD + (((ks * 4 + quad) ^ swz) << 3)];
            #pragma unroll
            for (int ni = 0; ni < 4; ++ni)
                #pragma unroll
                for (int mi = 0; mi < 2; ++mi)
                    acc[ni][mi] = __builtin_amdgcn_mfma_f32_16x16x32_bf16(
                        a[ni], qf[mi][ks], acc[ni][mi], 0, 0, 0);
        }

        // epilogue: per-lane partial accumulate (no shuffles, no LDS)
        const int n0 = ti * NTILE;
        if (n0 + NTILE <= NT) {
            #pragma unroll
            for (int ni = 0; ni < 4; ++ni)
                #pragma unroll
                for (int mi = 0; mi < 2; ++mi)
                    #pragma unroll
                    for (int r = 0; r < 4; ++r) {
                        float d = __builtin_amdgcn_sqrtf(
                            fmaxf(fmaf(-2.f, acc[ni][mi][r], 2.f), 0.f));
                        float e = __expf(-10.f * d);
                        se[mi] += e;
                        sd[mi] = fmaf(e, d, sd[mi]);
                    }
        } else {
            #pragma unroll
            for (int ni = 0; ni < 4; ++ni)
                #pragma unroll
                for (int mi = 0; mi < 2; ++mi)
                    #pragma unroll
                    for (int r = 0; r < 4; ++r) {
                        float d = __builtin_amdgcn_sqrtf(
                            fmaxf(fmaf(-2.f, acc[ni][mi][r], 2.f), 0.f));
                        bool valid = (n0 + ni * 16 + quad * 4 + r) < NT;
                        float e = valid ? __expf(-10.f * d) : 0.f;
                        se[mi] += e;
                        sd[mi] = fmaf(e, d, sd[mi]);
                    }
        }

        __syncthreads();   // waves done with cur; next-buf DMA drained
        cur ^= 1;
    }

    // ---- end: quad-reduce (2 shuffles) + replicated atomics ----
    float* ae = accs + (size_t)(blockIdx.x & (REPS - 1)) * 2048;
    float* ad = ae + 1024;
    #pragma unroll
    for (int mi = 0; mi < 2; ++mi) {
        float e = se[mi], d = sd[mi];
        e += __shfl_xor(e, 16, 64); e += __shfl_xor(e, 32, 64);
        d += __shfl_xor(d, 16, 64); d += __shfl_xor(d, 32, 64);
        if (quad == 0) {
            atomicAdd(&ae[mrow0 + mi * 16 + l16], e);
            atomicAdd(&ad[mrow0 + mi * 16 + l16], d);
        }
    }

    // ---- done-counter finalize ----
    __threadfence();
    __syncthreads();
    if (tid == 0) s_last = (atomicAdd(&cnts[0], 1) == GRID - 1) ? 1 : 0;
    __syncthreads();
    if (s_last) {
        for (int i = tid; i < BQ; i += 256) {
            float e = 0.f, d = 0.f;
            #pragma unroll
            for (int rp = 0; rp < REPS; ++rp) {
                e += __hip_atomic_load(&accs[rp * 2048 + i],
                                       __ATOMIC_RELAXED, __HIP_MEMORY_SCOPE_AGENT);
                d += __hip_atomic_load(&accs[rp * 2048 + 1024 + i],
                                       __ATOMIC_RELAXED, __HIP_MEMORY_SCOPE_AGENT);
            }
            out[i] = d / e;
        }
    }
}

extern "C" void kernel_launch(void* const* d_in, const int* in_sizes, int n_in,
                              void* d_out, int out_size, void* d_ws, size_t ws_size,
                              hipStream_t stream) {
    const float* q = (const float*)d_in[0];   // [1024,256] fp32
    const float* t = (const float*)d_in[1];   // [100000,256] fp32
    float* out = (float*)d_out;               // [1024] fp32

    char* ws = (char*)d_ws;
    float* accs = (float*)ws;                                   // REPS*2048 f = 64 KB
    int* cnts = (int*)(ws + (size_t)REPS * 2048 * sizeof(float));
    unsigned short* qn =
        (unsigned short*)(ws + (size_t)REPS * 2048 * sizeof(float) + 256);
    unsigned short* tn = qn + (size_t)BQ * DD;                  // 51.2 MB

    hipMemsetAsync(ws, 0, (size_t)REPS * 2048 * sizeof(float) + 256, stream);
    prep<<<(BQ + NT_PAD) / 4, 256, 0, stream>>>(q, t, qn, tn);
    knn_main<<<GRID, 256, 0, stream>>>(tn, qn, accs, cnts, out);
}